// Round 14
// baseline (152.760 us; speedup 1.0000x reference)
//
#include <hip/hip_runtime.h>
#include <stdint.h>

// DILATE loss, B=32, L=512, DIM=16, gamma=1e-3, alpha=0.5.
//
// Round-14 = R13's validated 4-wave pipelined wavefront, SKEW-2 columns:
//   kA : D[b][j][i] column-major, unskewed (proven fast form).
//   kP : one 256-thread block (4 waves) per batch. Lane tid owns rows
//        {2tid, 2tid+1}; at step s processes cols c0=2p, c1=2p+1 where
//        p = s - tid - 16w (560 steps vs R13's 864; 4 cells/lane/step --
//        R13 showed ~155 cyc/step FIXED overhead, so amortize it).
//        Within-wave handoff: DPP wave_shr of both columns' r1 values.
//        Cross-wave: 64-slot f32x2 ring (indexed by column), producer lane
//        63 writes one f32x4 {R(r1,c0),T,R(r1,c1),T} per step; consumer
//        lane 0 reads banks of 4 steps (4x f32x4), 4-7 steps ahead.
//        Lead = 17 steps; barrier every 8 -> write/read always barrier-
//        separated (gap 10-13 steps); slot reuse after 32 steps >> drift.
//        Loads: 8-slot asm FIFO, 2 global_load_dwordx2 per slot, counted
//        s_waitcnt vmcnt(14) with "+v" ties (R11/R13 proven mechanism).
//        Junk cells: clamped loads + fmax(D,0) + BIGF algebra (R13-proven).
//   kC : combine -> scalar loss.
// Tie priority (all passing rounds): diag > up > left.

#define N 512
#define NB 32
#define BIGF 1e10f
#define VOMAX (N * N * 4 - 8)

typedef unsigned int u32;
typedef float f32x4 __attribute__((ext_vector_type(4)));
typedef float f32x2 __attribute__((ext_vector_type(2)));

__device__ __forceinline__ float dppshr(float x, float oldv) {
    // lane l gets lane l-1's x; lane 0 keeps oldv (bound_ctrl=false)
    return __int_as_float(__builtin_amdgcn_update_dpp(
        __float_as_int(oldv), __float_as_int(x), 0x138, 0xF, 0xF, false));
}

// ---------------- kA: pairwise squared distances, column-major -------------
__global__ __launch_bounds__(512) void kA(const float* __restrict__ inp,
                                          const float* __restrict__ tgt,
                                          float* __restrict__ Dg) {
    const int b = blockIdx.y;
    const int jc = blockIdx.x;         // group of 4 columns
    const int tid = (int)threadIdx.x;  // row index i in [0,512)
    __shared__ float xs[4][16];        // x[j] = inp[b,j]-inp[b,0]
    if (tid < 64) {
        int c = tid >> 4, d = tid & 15;
        int j = jc * 4 + c;
        xs[c][d] = inp[(((size_t)b * N + j) << 4) + d] -
                   inp[(((size_t)b * N) << 4) + d];
    }
    __syncthreads();
    const float4* t4 = (const float4*)(tgt + (((size_t)b * N + tid) << 4));
    float4 ta = t4[0], tb = t4[1], tc = t4[2], td = t4[3];
    float* out = Dg + (size_t)b * (N * N) + (size_t)jc * 4 * N + tid;
#pragma unroll
    for (int c = 0; c < 4; ++c) {
        float s = 0.f, e;
        e = ta.x - xs[c][0];  s = fmaf(e, e, s);
        e = ta.y - xs[c][1];  s = fmaf(e, e, s);
        e = ta.z - xs[c][2];  s = fmaf(e, e, s);
        e = ta.w - xs[c][3];  s = fmaf(e, e, s);
        e = tb.x - xs[c][4];  s = fmaf(e, e, s);
        e = tb.y - xs[c][5];  s = fmaf(e, e, s);
        e = tb.z - xs[c][6];  s = fmaf(e, e, s);
        e = tb.w - xs[c][7];  s = fmaf(e, e, s);
        e = tc.x - xs[c][8];  s = fmaf(e, e, s);
        e = tc.y - xs[c][9];  s = fmaf(e, e, s);
        e = tc.z - xs[c][10]; s = fmaf(e, e, s);
        e = tc.w - xs[c][11]; s = fmaf(e, e, s);
        e = td.x - xs[c][12]; s = fmaf(e, e, s);
        e = td.y - xs[c][13]; s = fmaf(e, e, s);
        e = td.z - xs[c][14]; s = fmaf(e, e, s);
        e = td.w - xs[c][15]; s = fmaf(e, e, s);
        out[(size_t)c * N] = s;
    }
}

// ---------------- kP: 4-wave skew-2 pipelined wavefront DP -----------------
__global__ __launch_bounds__(256) void kP(const float* __restrict__ Dg,
                                          float* __restrict__ acc) {
    const int b = blockIdx.x;
    const int tid = (int)threadIdx.x;
    const int w = tid >> 6, lam = tid & 63;
    const float* __restrict__ Db = Dg + (size_t)b * (N * N);

    __shared__ __align__(16) f32x2 ring[3][64];
    __shared__ __align__(16) f32x2 dump2[72];

    for (int i = tid; i < 3 * 64 + 72; i += 256) {
        f32x2 z; z.x = BIGF; z.y = 0.f;
        ((f32x2*)ring)[i] = z;
    }
    __syncthreads();

    // 8 load slots; slot k covers steps s == k (mod 8).
    // col c0(s) = 2(s - tid - 16w); voA = c0*2048 + tid*8 (clamped at issue)
    int voA0, voA1, voA2, voA3, voA4, voA5, voA6, voA7;
    f32x2 dA0, dA1, dA2, dA3, dA4, dA5, dA6, dA7;
    f32x2 dB0, dB1, dB2, dB3, dB4, dB5, dB6, dB7;
    {
        const int vb = tid * 8 - (tid + 16 * w) * 4096;
        voA0 = vb;            voA1 = vb + 4096;     voA2 = vb + 2 * 4096;
        voA3 = vb + 3 * 4096; voA4 = vb + 4 * 4096; voA5 = vb + 5 * 4096;
        voA6 = vb + 6 * 4096; voA7 = vb + 7 * 4096;
    }

#define LOAD(k)                                                               \
    do {                                                                      \
        int va_ = min(max(voA##k, 0), VOMAX);                                 \
        int vc_ = min(max(voA##k + 2048, 0), VOMAX);                          \
        asm volatile("global_load_dwordx2 %0, %2, %4\n\t"                     \
                     "global_load_dwordx2 %1, %3, %4"                         \
                     : "=v"(dA##k), "=v"(dB##k)                               \
                     : "v"(va_), "v"(vc_), "s"(Db));                          \
    } while (0)

    LOAD(0); LOAD(1); LOAD(2); LOAD(3); LOAD(4); LOAD(5); LOAD(6); LOAD(7);

    // DP state
    float L0R = BIGF, L1R = BIGF, L0T = 0.f, L1T = 0.f;  // own cols at c1
    float hA = BIGF, hB = BIGF, hAT = 0.f, hBT = 0.f;    // dpp handoffs
    float sBold = (tid == 0) ? 0.f : BIGF, sBoldT = 0.f; // diag for (r0,c0)
    float dr = (float)(4 * tid + 32 * w);                // (i-j) at (r0,c0)
    int pp = -(tid + 16 * w);                            // pair index
    float Rfin = 0.f, Tfin = 0.f;

    const bool is_cons = (lam == 0) && (w > 0);
    f32x2* base2 = ((lam == 63) && (w < 3)) ? &ring[w][0] : &dump2[0];
    const f32x2* ringR = (w > 0) ? &ring[w - 1][0] : &ring[0][0];
    int rb = (-160 * w) & 63;

    f32x4 bkA[4], bkB[4];

#define READBANK(X)                                                           \
    do {                                                                      \
        if (is_cons) {                                                        \
            X[0] = *(const f32x4*)(ringR + (rb & 63));                        \
            X[1] = *(const f32x4*)(ringR + ((rb + 2) & 63));                  \
            X[2] = *(const f32x4*)(ringR + ((rb + 4) & 63));                  \
            X[3] = *(const f32x4*)(ringR + ((rb + 6) & 63));                  \
        }                                                                     \
        rb = (rb + 8) & 63;                                                   \
    } while (0)

    READBANK(bkA);  // prime: handoff data for steps 0..3

#define STEP(k, BX, j)                                                        \
    do {                                                                      \
        asm volatile("s_waitcnt vmcnt(14)" : "+v"(dA##k), "+v"(dB##k));       \
        float D00 = fmaxf(dA##k.x, 0.f), D10 = fmaxf(dA##k.y, 0.f);           \
        float D01 = fmaxf(dB##k.x, 0.f), D11 = fmaxf(dB##k.y, 0.f);           \
        float upA = is_cons ? BX[j].x : hA;                                   \
        float utA = is_cons ? BX[j].y : hAT;                                  \
        float upB = is_cons ? BX[j].z : hB;                                   \
        float utB = is_cons ? BX[j].w : hBT;                                  \
        /* (r0,c0): up=upA dg=sBold lf=L0 */                                  \
        float mn0 = fminf(upA, fminf(sBold, L0R));                            \
        float Ts0 = (mn0 == sBold) ? sBoldT : ((mn0 == upA) ? utA : L0T);     \
        float R00 = D00 + mn0;                                                \
        float T00 = fmaf(dr, dr, Ts0);                                        \
        /* (r1,c0): up=R00 dg=L0 lf=L1 */                                     \
        float mn1 = fminf(R00, fminf(L0R, L1R));                              \
        float Ts1 = (mn1 == L0R) ? L0T : ((mn1 == R00) ? T00 : L1T);          \
        float drp = dr + 1.f;                                                 \
        float R10 = D10 + mn1;                                                \
        float T10 = fmaf(drp, drp, Ts1);                                      \
        /* (r0,c1): up=upB dg=upA lf=R00 */                                   \
        float mn2 = fminf(upB, fminf(upA, R00));                              \
        float Ts2 = (mn2 == upA) ? utA : ((mn2 == upB) ? utB : T00);          \
        float drm = dr - 1.f;                                                 \
        float R01 = D01 + mn2;                                                \
        float T01 = fmaf(drm, drm, Ts2);                                      \
        /* (r1,c1): up=R01 dg=R00 lf=R10 */                                   \
        float mn3 = fminf(R01, fminf(R00, R10));                              \
        float Ts3 = (mn3 == R00) ? T00 : ((mn3 == R01) ? T01 : T10);          \
        float R11v = D11 + mn3;                                               \
        float T11v = fmaf(dr, dr, Ts3);                                       \
        bool hit = (pp == 255);                                               \
        Rfin = hit ? R11v : Rfin;                                             \
        Tfin = hit ? T11v : Tfin;                                             \
        /* ring write: producer -> ring[w], others -> dump; junk cols may   */\
        /* alias ring slots only AFTER consumers are done (lead analysis)   */\
        {                                                                     \
            int c0_ = 2 * pp;                                                 \
            f32x4 wv; wv.x = R10; wv.y = T10; wv.z = R11v; wv.w = T11v;       \
            *(f32x4*)(base2 + (c0_ & 63)) = wv;                               \
        }                                                                     \
        L0R = R01; L0T = T01; L1R = R11v; L1T = T11v;                         \
        sBold = upB; sBoldT = utB;                                            \
        hA = dppshr(R10, BIGF); hAT = dppshr(T10, 0.f);                       \
        hB = dppshr(R11v, BIGF); hBT = dppshr(T11v, 0.f);                     \
        dr -= 2.f; pp += 1;                                                   \
        voA##k += 32768; /* +16 cols for this slot's next use */              \
        LOAD(k);                                                              \
    } while (0)

    for (int n = 0; n < 70; ++n) {  // 560 steps; lane 255 capture at s=558
        asm volatile("s_waitcnt lgkmcnt(0)" ::: "memory");
        __builtin_amdgcn_s_barrier();
        READBANK(bkB);  // handoff data for steps 8n+4..8n+7
        STEP(0, bkA, 0); STEP(1, bkA, 1); STEP(2, bkA, 2); STEP(3, bkA, 3);
        READBANK(bkA);  // handoff data for steps 8(n+1)..8(n+1)+3
        STEP(4, bkB, 0); STEP(5, bkB, 1); STEP(6, bkB, 2); STEP(7, bkB, 3);
    }
#undef STEP
#undef READBANK
#undef LOAD

    asm volatile("s_waitcnt vmcnt(0)" ::: "memory");  // drain before exit
    if (tid == 255) {
        acc[b] = Rfin;       // hard-DTW value Rp[N,N]
        acc[NB + b] = Tfin;  // sum (i-j)^2 along argmin path
    }
}

// ---------------- kC: combine over batches ---------------------------------
__global__ void kC(const float* __restrict__ acc, float* __restrict__ out) {
    const int l = (int)threadIdx.x;
    float vs = (l < NB) ? acc[l] : 0.f;
    float vt = (l < NB) ? acc[NB + l] : 0.f;
#pragma unroll
    for (int o = 32; o >= 1; o >>= 1) {
        vs += __shfl_down(vs, o);
        vt += __shfl_down(vt, o);
    }
    if (l == 0)
        out[0] = 0.5f * (vs / (float)NB) +
                 0.5f * (vt / ((float)NB * (float)(N * N)));
}

__global__ void kSentinel(float* out) { out[0] = -12345.0f; }

extern "C" void kernel_launch(void* const* d_in, const int* in_sizes, int n_in,
                              void* d_out, int out_size, void* d_ws, size_t ws_size,
                              hipStream_t stream) {
    const float* inp = (const float*)d_in[0];
    const float* tgt = (const float*)d_in[1];
    float* out = (float*)d_out;

    const size_t DSZ = (size_t)NB * N * N * sizeof(float);  // 32 MiB
    const size_t NEEDED = 256 + DSZ;
    if (ws_size < NEEDED) {
        kSentinel<<<1, 1, 0, stream>>>(out);
        return;
    }
    char* ws = (char*)d_ws;
    float* acc = (float*)ws;  // [0..31] shape, [32..63] temporal
    float* Dg = (float*)(ws + 256);

    kA<<<dim3(N / 4, NB), 512, 0, stream>>>(inp, tgt, Dg);
    kP<<<NB, 256, 0, stream>>>(Dg, acc);
    kC<<<1, 64, 0, stream>>>(acc, out);
}

// Round 15
// 106.095 us; speedup vs baseline: 1.4398x; 1.4398x over previous
//
#include <hip/hip_runtime.h>
#include <stdint.h>

// DILATE loss, B=32, L=512, DIM=16, gamma=1e-3, alpha=0.5.
//
// Round-15 = R14's 4-wave skew-2 DP (absmax 0.0 validated) with COALESCED
// loads via a doubly-skewed layout (R13's lesson: scattered per-lane loads
// serialize in L1 at ~1 line/cyc/CU; R14 paid ~512 cyc/step for them).
//
//   kA : Dsk2[b][q][i*2+(j&1)], q = j/2 + i/2 in [0,510] (512 alloc).
//        Per (i, col-pair) one float2 write.
//   kP : one 256-thread block (4 waves) per batch. Lane tid owns rows
//        {2tid,2tid+1}; step s processes cols c0=2p,c1=2p+1, p=s-tid-16w
//        (560 steps). Load: ONE global_load_dwordx4 at lane-uniform block
//        q=s-16w, byte q*4096+tid*16 -> 1024B contiguous per wave-step.
//        8 asm slots, counted s_waitcnt vmcnt(7) with "+v" ties.
//        DP math/ring/barrier/junk handling verbatim from R14.
//   kC : combine -> scalar loss.
// Junk cells: clamped loads / 0xAA poison (-3e-13) -> fmax(D,0)=0 ->
// R_junk = 0 + 1e10 = 1e10 exactly (ulp(1e10)=1024); inert (R13-proven).
// Tie priority (all passing rounds): diag > up > left.

#define N 512
#define NB 32
#define BIGF 1e10f
#define QN 512
#define STRF2 ((size_t)QN * 1024)      // floats per batch (2 MiB)
#define VOMAX2 ((int)(STRF2 * 4 - 16))

typedef unsigned int u32;
typedef float f32x4 __attribute__((ext_vector_type(4)));
typedef float f32x2 __attribute__((ext_vector_type(2)));

__device__ __forceinline__ float dppshr(float x, float oldv) {
    // lane l gets lane l-1's x; lane 0 keeps oldv (bound_ctrl=false)
    return __int_as_float(__builtin_amdgcn_update_dpp(
        __float_as_int(oldv), __float_as_int(x), 0x138, 0xF, 0xF, false));
}

// ---------------- kA: pairwise squared distances -> doubly-skewed ----------
__global__ __launch_bounds__(512) void kA(const float* __restrict__ inp,
                                          const float* __restrict__ tgt,
                                          float* __restrict__ Dg) {
    const int b = blockIdx.y;
    const int jc = blockIdx.x;         // group of 4 columns
    const int tid = (int)threadIdx.x;  // row index i in [0,512)
    __shared__ float xs[4][16];        // x[j] = inp[b,j]-inp[b,0]
    if (tid < 64) {
        int c = tid >> 4, d = tid & 15;
        int j = jc * 4 + c;
        xs[c][d] = inp[(((size_t)b * N + j) << 4) + d] -
                   inp[(((size_t)b * N) << 4) + d];
    }
    __syncthreads();
    const float4* t4 = (const float4*)(tgt + (((size_t)b * N + tid) << 4));
    float4 ta = t4[0], tb = t4[1], tc = t4[2], td = t4[3];
    float s[4];
#pragma unroll
    for (int c = 0; c < 4; ++c) {
        float acc = 0.f, e;
        e = ta.x - xs[c][0];  acc = fmaf(e, e, acc);
        e = ta.y - xs[c][1];  acc = fmaf(e, e, acc);
        e = ta.z - xs[c][2];  acc = fmaf(e, e, acc);
        e = ta.w - xs[c][3];  acc = fmaf(e, e, acc);
        e = tb.x - xs[c][4];  acc = fmaf(e, e, acc);
        e = tb.y - xs[c][5];  acc = fmaf(e, e, acc);
        e = tb.z - xs[c][6];  acc = fmaf(e, e, acc);
        e = tb.w - xs[c][7];  acc = fmaf(e, e, acc);
        e = tc.x - xs[c][8];  acc = fmaf(e, e, acc);
        e = tc.y - xs[c][9];  acc = fmaf(e, e, acc);
        e = tc.z - xs[c][10]; acc = fmaf(e, e, acc);
        e = tc.w - xs[c][11]; acc = fmaf(e, e, acc);
        e = td.x - xs[c][12]; acc = fmaf(e, e, acc);
        e = td.y - xs[c][13]; acc = fmaf(e, e, acc);
        e = td.z - xs[c][14]; acc = fmaf(e, e, acc);
        e = td.w - xs[c][15]; acc = fmaf(e, e, acc);
        s[c] = acc;
    }
    // write two float2s: col-pairs (jc*4, +1) and (jc*4+2, +3)
    float* outB = Dg + (size_t)b * STRF2;
    const int q0 = jc * 2 + (tid >> 1);
    f32x2 w0; w0.x = s[0]; w0.y = s[1];
    f32x2 w1; w1.x = s[2]; w1.y = s[3];
    *(f32x2*)(outB + (size_t)q0 * 1024 + tid * 2) = w0;
    *(f32x2*)(outB + (size_t)(q0 + 1) * 1024 + tid * 2) = w1;
}

// ---------------- kP: 4-wave skew-2 pipelined wavefront DP -----------------
__global__ __launch_bounds__(256) void kP(const float* __restrict__ Dg,
                                          float* __restrict__ acc) {
    const int b = blockIdx.x;
    const int tid = (int)threadIdx.x;
    const int w = tid >> 6, lam = tid & 63;
    const float* __restrict__ Db = Dg + (size_t)b * STRF2;

    __shared__ __align__(16) f32x2 ring[3][64];
    __shared__ __align__(16) f32x2 dump2[72];

    for (int i = tid; i < 3 * 64 + 72; i += 256) {
        f32x2 z; z.x = BIGF; z.y = 0.f;
        ((f32x2*)ring)[i] = z;
    }
    __syncthreads();

    // 8 load slots; slot k covers steps s == k (mod 8).
    // voffset = (s - 16w)*4096 + tid*16, clamped at issue.
    int vo0, vo1, vo2, vo3, vo4, vo5, vo6, vo7;
    f32x4 d0, d1, d2, d3, d4, d5, d6, d7;
    {
        const int vb = tid * 16 - 16 * w * 4096;
        vo0 = vb;            vo1 = vb + 4096;     vo2 = vb + 2 * 4096;
        vo3 = vb + 3 * 4096; vo4 = vb + 4 * 4096; vo5 = vb + 5 * 4096;
        vo6 = vb + 6 * 4096; vo7 = vb + 7 * 4096;
    }

#define LOAD(k)                                                               \
    do {                                                                      \
        int va_ = min(max(vo##k, 0), VOMAX2);                                 \
        asm volatile("global_load_dwordx4 %0, %1, %2"                         \
                     : "=v"(d##k) : "v"(va_), "s"(Db));                       \
    } while (0)

    LOAD(0); LOAD(1); LOAD(2); LOAD(3); LOAD(4); LOAD(5); LOAD(6); LOAD(7);

    // DP state (R14 semantics verbatim)
    float L0R = BIGF, L1R = BIGF, L0T = 0.f, L1T = 0.f;  // own cols at c1
    float hA = BIGF, hB = BIGF, hAT = 0.f, hBT = 0.f;    // dpp handoffs
    float sBold = (tid == 0) ? 0.f : BIGF, sBoldT = 0.f; // diag for (r0,c0)
    float dr = (float)(4 * tid + 32 * w);                // (i-j) at (r0,c0)
    int pp = -(tid + 16 * w);                            // pair index
    float Rfin = 0.f, Tfin = 0.f;

    const bool is_cons = (lam == 0) && (w > 0);
    f32x2* base2 = ((lam == 63) && (w < 3)) ? &ring[w][0] : &dump2[0];
    const f32x2* ringR = (w > 0) ? &ring[w - 1][0] : &ring[0][0];
    int rb = (-160 * w) & 63;

    f32x4 bkA[4], bkB[4];

#define READBANK(X)                                                           \
    do {                                                                      \
        if (is_cons) {                                                        \
            X[0] = *(const f32x4*)(ringR + (rb & 63));                        \
            X[1] = *(const f32x4*)(ringR + ((rb + 2) & 63));                  \
            X[2] = *(const f32x4*)(ringR + ((rb + 4) & 63));                  \
            X[3] = *(const f32x4*)(ringR + ((rb + 6) & 63));                  \
        }                                                                     \
        rb = (rb + 8) & 63;                                                   \
    } while (0)

    READBANK(bkA);  // prime: handoff data for steps 0..3

    // d layout: d.x=D(r0,c0) d.y=D(r0,c1) d.z=D(r1,c0) d.w=D(r1,c1)
#define STEP(k, BX, j)                                                        \
    do {                                                                      \
        asm volatile("s_waitcnt vmcnt(7)" : "+v"(d##k));                      \
        float D00 = fmaxf(d##k.x, 0.f), D01 = fmaxf(d##k.y, 0.f);             \
        float D10 = fmaxf(d##k.z, 0.f), D11 = fmaxf(d##k.w, 0.f);             \
        float upA = is_cons ? BX[j].x : hA;                                   \
        float utA = is_cons ? BX[j].y : hAT;                                  \
        float upB = is_cons ? BX[j].z : hB;                                   \
        float utB = is_cons ? BX[j].w : hBT;                                  \
        /* (r0,c0): up=upA dg=sBold lf=L0 */                                  \
        float mn0 = fminf(upA, fminf(sBold, L0R));                            \
        float Ts0 = (mn0 == sBold) ? sBoldT : ((mn0 == upA) ? utA : L0T);     \
        float R00 = D00 + mn0;                                                \
        float T00 = fmaf(dr, dr, Ts0);                                        \
        /* (r1,c0): up=R00 dg=L0 lf=L1 */                                     \
        float mn1 = fminf(R00, fminf(L0R, L1R));                              \
        float Ts1 = (mn1 == L0R) ? L0T : ((mn1 == R00) ? T00 : L1T);          \
        float drp = dr + 1.f;                                                 \
        float R10 = D10 + mn1;                                                \
        float T10 = fmaf(drp, drp, Ts1);                                      \
        /* (r0,c1): up=upB dg=upA lf=R00 */                                   \
        float mn2 = fminf(upB, fminf(upA, R00));                              \
        float Ts2 = (mn2 == upA) ? utA : ((mn2 == upB) ? utB : T00);          \
        float drm = dr - 1.f;                                                 \
        float R01 = D01 + mn2;                                                \
        float T01 = fmaf(drm, drm, Ts2);                                      \
        /* (r1,c1): up=R01 dg=R00 lf=R10 */                                   \
        float mn3 = fminf(R01, fminf(R00, R10));                              \
        float Ts3 = (mn3 == R00) ? T00 : ((mn3 == R01) ? T01 : T10);          \
        float R11v = D11 + mn3;                                               \
        float T11v = fmaf(dr, dr, Ts3);                                       \
        bool hit = (pp == 255);                                               \
        Rfin = hit ? R11v : Rfin;                                             \
        Tfin = hit ? T11v : Tfin;                                             \
        {                                                                     \
            int c0_ = 2 * pp;                                                 \
            f32x4 wv; wv.x = R10; wv.y = T10; wv.z = R11v; wv.w = T11v;       \
            *(f32x4*)(base2 + (c0_ & 63)) = wv;                               \
        }                                                                     \
        L0R = R01; L0T = T01; L1R = R11v; L1T = T11v;                         \
        sBold = upB; sBoldT = utB;                                            \
        hA = dppshr(R10, BIGF); hAT = dppshr(T10, 0.f);                       \
        hB = dppshr(R11v, BIGF); hBT = dppshr(T11v, 0.f);                     \
        dr -= 2.f; pp += 1;                                                   \
        vo##k += 32768; /* +8 q-blocks for this slot's next use */            \
        LOAD(k);                                                              \
    } while (0)

    for (int n = 0; n < 70; ++n) {  // 560 steps; lane 255 capture at s=558
        asm volatile("s_waitcnt lgkmcnt(0)" ::: "memory");
        __builtin_amdgcn_s_barrier();
        READBANK(bkB);  // handoff data for steps 8n+4..8n+7
        STEP(0, bkA, 0); STEP(1, bkA, 1); STEP(2, bkA, 2); STEP(3, bkA, 3);
        READBANK(bkA);  // handoff data for steps 8(n+1)..8(n+1)+3
        STEP(4, bkB, 0); STEP(5, bkB, 1); STEP(6, bkB, 2); STEP(7, bkB, 3);
    }
#undef STEP
#undef READBANK
#undef LOAD

    asm volatile("s_waitcnt vmcnt(0)" ::: "memory");  // drain before exit
    if (tid == 255) {
        acc[b] = Rfin;       // hard-DTW value Rp[N,N]
        acc[NB + b] = Tfin;  // sum (i-j)^2 along argmin path
    }
}

// ---------------- kC: combine over batches ---------------------------------
__global__ void kC(const float* __restrict__ acc, float* __restrict__ out) {
    const int l = (int)threadIdx.x;
    float vs = (l < NB) ? acc[l] : 0.f;
    float vt = (l < NB) ? acc[NB + l] : 0.f;
#pragma unroll
    for (int o = 32; o >= 1; o >>= 1) {
        vs += __shfl_down(vs, o);
        vt += __shfl_down(vt, o);
    }
    if (l == 0)
        out[0] = 0.5f * (vs / (float)NB) +
                 0.5f * (vt / ((float)NB * (float)(N * N)));
}

__global__ void kSentinel(float* out) { out[0] = -12345.0f; }

extern "C" void kernel_launch(void* const* d_in, const int* in_sizes, int n_in,
                              void* d_out, int out_size, void* d_ws, size_t ws_size,
                              hipStream_t stream) {
    const float* inp = (const float*)d_in[0];
    const float* tgt = (const float*)d_in[1];
    float* out = (float*)d_out;

    const size_t DSZ = (size_t)NB * STRF2 * sizeof(float);  // 64 MiB
    const size_t NEEDED = 256 + DSZ;
    if (ws_size < NEEDED) {
        kSentinel<<<1, 1, 0, stream>>>(out);
        return;
    }
    char* ws = (char*)d_ws;
    float* acc = (float*)ws;  // [0..31] shape, [32..63] temporal
    float* Dg = (float*)(ws + 256);

    kA<<<dim3(N / 4, NB), 512, 0, stream>>>(inp, tgt, Dg);
    kP<<<NB, 256, 0, stream>>>(Dg, acc);
    kC<<<1, 64, 0, stream>>>(acc, out);
}